// Round 7
// baseline (805.029 us; speedup 1.0000x reference)
//
#include <hip/hip_runtime.h>

// ---------------------------------------------------------------------------
// TransformerBlock: B=2,S=2048,D=2048,H=32,HD=64,G=8,KV=256,DFF=5632
// fp32 in/out. R7: attention V-path rebuilt: V pre-transposed (vt_kernel,
// 2MB into the act region, free during attn) so attn stages V with 2 uint4
// loads/lane/tile instead of 16 scalar gathers + 8 pack ops; Q fragments
// (loop-invariant) hoisted out of the kt loop (-128 ds_read/lane).
// GEMMs unchanged from R6 (m97-form BK=64 + XOR swizzle; fused SwiGLU).
// ---------------------------------------------------------------------------

typedef __attribute__((ext_vector_type(8))) __bf16 bf16x8;
typedef __attribute__((ext_vector_type(4))) __bf16 bf16x4;
typedef __attribute__((ext_vector_type(4))) float f32x4;

#define RR 4096      // B*S rows
#define DD 2048
#define KVD 256
#define QKVN 2560    // 2048 q + 256 k + 256 v
#define DFF 5632

// ---------------- workspace layout (bytes) ----------------
static const size_t OFF_WQKV = 0;              // bf16 [2560,2048]
static const size_t OFF_WO   = 10485760;       // bf16 [2048,2048]
static const size_t OFF_WG   = 18874368;       // bf16 [5632,2048]
static const size_t OFF_WU   = 41943040;       // bf16 [5632,2048]
static const size_t OFF_WDN  = 65011712;       // bf16 [2048,5632]
static const size_t OFF_H    = 88080384;       // bf16 [4096,2048]  (h, then attn_out)
static const size_t OFF_QKV  = 104857600;      // bf16 [4096,2560]
static const size_t OFF_Q    = 125829120;      // bf16 [4096,2048]  (q_rope, then h2)
static const size_t OFF_K    = 142606336;      // bf16 [4096,256]
static const size_t OFF_ACT  = 144703488;      // bf16 [4096,5632]  (V^T during attn; silu*up in FFN)
static const size_t WS_NEED  = 190840832;

// ---------------- async global->LDS 16B ----------------
__device__ __forceinline__ void glds16(const __bf16* g, __bf16* s) {
  __builtin_amdgcn_global_load_lds(
      (const __attribute__((address_space(1))) unsigned int*)(const void*)g,
      (__attribute__((address_space(3))) unsigned int*)(void*)s, 16, 0, 0);
}

// ---------------- fp32 -> bf16 convert, all weights in one launch ----------
__global__ __launch_bounds__(256)
void cvt_all_kernel(const float* __restrict__ wq, const float* __restrict__ wk,
                    const float* __restrict__ wv, const float* __restrict__ wo,
                    const float* __restrict__ wg, const float* __restrict__ wu,
                    const float* __restrict__ wd, __bf16* __restrict__ wqkv,
                    __bf16* __restrict__ wob, __bf16* __restrict__ wgb,
                    __bf16* __restrict__ wub, __bf16* __restrict__ wdb) {
  int i = blockIdx.x * 256 + threadIdx.x;
  const float* s; __bf16* d; int si, di;
  if (i < 1048576)      { s = wq; d = wqkv; si = i;           di = i; }
  else if (i < 1179648) { s = wk; d = wqkv; si = i - 1048576; di = i; }
  else if (i < 1310720) { s = wv; d = wqkv; si = i - 1179648; di = i; }
  else if (i < 2359296) { s = wo; d = wob;  si = i - 1310720; di = si; }
  else if (i < 5242880) { s = wg; d = wgb;  si = i - 2359296; di = si; }
  else if (i < 8126464) { s = wu; d = wub;  si = i - 5242880; di = si; }
  else                  { s = wd; d = wdb;  si = i - 8126464; di = si; }
  float4 v = ((const float4*)s)[si];
  union { __bf16 b[4]; ushort4 u; } c;
  c.b[0] = (__bf16)v.x; c.b[1] = (__bf16)v.y; c.b[2] = (__bf16)v.z; c.b[3] = (__bf16)v.w;
  ((ushort4*)d)[di] = c.u;
}

// ---------------- RMSNorm (row of 2048, 256 threads) ----------------
__global__ __launch_bounds__(256)
void rmsnorm_kernel(const float* __restrict__ x, const float* __restrict__ w,
                    __bf16* __restrict__ out) {
  const int row = blockIdx.x, t = threadIdx.x;
  const float4* xr = (const float4*)(x + (size_t)row * DD);
  float4 a = xr[t], b = xr[t + 256];
  float s = a.x*a.x + a.y*a.y + a.z*a.z + a.w*a.w
          + b.x*b.x + b.y*b.y + b.z*b.z + b.w*b.w;
#pragma unroll
  for (int m = 1; m < 64; m <<= 1) s += __shfl_xor(s, m, 64);
  __shared__ float red[4];
  if ((t & 63) == 0) red[t >> 6] = s;
  __syncthreads();
  float tot = red[0] + red[1] + red[2] + red[3];
  float inv = 1.0f / (sqrtf(tot * (1.0f / 2048.0f) + 1e-6f) + 1e-6f);
  const float4* wr = (const float4*)w;
  float4 w0 = wr[t], w1 = wr[t + 256];
  __bf16* o = out + (size_t)row * DD;
  union { __bf16 bb[4]; ushort4 u; } c;
  c.bb[0] = (__bf16)(a.x*inv*w0.x); c.bb[1] = (__bf16)(a.y*inv*w0.y);
  c.bb[2] = (__bf16)(a.z*inv*w0.z); c.bb[3] = (__bf16)(a.w*inv*w0.w);
  ((ushort4*)o)[t] = c.u;
  c.bb[0] = (__bf16)(b.x*inv*w1.x); c.bb[1] = (__bf16)(b.y*inv*w1.y);
  c.bb[2] = (__bf16)(b.z*inv*w1.z); c.bb[3] = (__bf16)(b.w*inv*w1.w);
  ((ushort4*)o)[t + 256] = c.u;
}

// ---------------- NT GEMM: C[M,N] = A[M,K] * B[N,K]^T ----------------
// R5-proven: 128x128 tile, BK=64, 256 thr, XOR slot swizzle (0 conflicts).
template<int EPI>
__global__ __launch_bounds__(256)
void gemm_nt_kernel(const __bf16* __restrict__ A, const __bf16* __restrict__ Bm,
                    __bf16* Cb, const float* __restrict__ Res,
                    float* __restrict__ Cf, int M, int N, int K) {
  __shared__ __align__(16) __bf16 As[128 * 64];
  __shared__ __align__(16) __bf16 Bs[128 * 64];
  const int t = threadIdx.x;
  const int GM = M >> 7, GN = N >> 7;
  int m_t, n_t;
  if (GM == 32 && (GN & 3) == 0) {
    int lid = blockIdx.y * gridDim.x + blockIdx.x;
    int xcd = lid & 7, i = lid >> 3;
    int c = i >> 4, j = i & 15;
    m_t = xcd * 4 + (j & 3);
    n_t = c * 4 + (j >> 2);
  } else {
    m_t = blockIdx.y; n_t = blockIdx.x;
  }
  const int m0 = m_t * 128, n0 = n_t * 128;
  const int w = t >> 6, l = t & 63;
  const int wm = w & 1, wn = w >> 1;
  const int lm = l & 15, lq = l >> 4;
  const int srow = w * 8 + (l >> 3);
  const int sslot = (l & 7) ^ (l >> 3);
  const __bf16* Ap = A + (size_t)(m0 + srow) * K + sslot * 8;
  const __bf16* Bp = Bm + (size_t)(n0 + srow) * K + sslot * 8;
  __bf16* AsW = As + w * 512;
  __bf16* BsW = Bs + w * 512;
  const int sl0 = ((lq) ^ (lm & 7)) << 3;
  const int sl1 = ((4 + lq) ^ (lm & 7)) << 3;
  f32x4 acc[4][4] = {};
  for (int kt = 0; kt < K; kt += 64) {
    __syncthreads();
#pragma unroll
    for (int it = 0; it < 4; it++) {
      glds16(Ap + (size_t)(it * 32) * K + kt, AsW + it * 2048);
      glds16(Bp + (size_t)(it * 32) * K + kt, BsW + it * 2048);
    }
    __syncthreads();
    bf16x8 af[2][4], bfr[2][4];
#pragma unroll
    for (int i = 0; i < 4; i++) {
      af[0][i]  = *(const bf16x8*)&As[(wm * 64 + i * 16 + lm) * 64 + sl0];
      af[1][i]  = *(const bf16x8*)&As[(wm * 64 + i * 16 + lm) * 64 + sl1];
      bfr[0][i] = *(const bf16x8*)&Bs[(wn * 64 + i * 16 + lm) * 64 + sl0];
      bfr[1][i] = *(const bf16x8*)&Bs[(wn * 64 + i * 16 + lm) * 64 + sl1];
    }
#pragma unroll
    for (int kk = 0; kk < 2; kk++)
#pragma unroll
      for (int i = 0; i < 4; i++)
#pragma unroll
        for (int j = 0; j < 4; j++)
          acc[i][j] = __builtin_amdgcn_mfma_f32_16x16x32_bf16(af[kk][i], bfr[kk][j], acc[i][j], 0, 0, 0);
  }
#pragma unroll
  for (int i = 0; i < 4; i++)
#pragma unroll
    for (int j = 0; j < 4; j++)
#pragma unroll
      for (int r = 0; r < 4; r++) {
        int row = m0 + wm * 64 + i * 16 + lq * 4 + r;
        int col = n0 + wn * 64 + j * 16 + lm;
        size_t idx = (size_t)row * N + col;
        if (EPI == 0) {
          Cb[idx] = (__bf16)acc[i][j][r];
        } else {
          Cf[idx] = Res[idx] + acc[i][j][r];
        }
      }
}

// ---------------- fused SwiGLU GEMM: act = silu(A*G^T) * (A*U^T) ----------
__global__ __launch_bounds__(512)
void gemm_glu_kernel(const __bf16* __restrict__ A, const __bf16* __restrict__ Gm,
                     const __bf16* __restrict__ Um, __bf16* __restrict__ Cb,
                     int M, int N, int K) {
  __shared__ __align__(16) __bf16 As[128 * 64];
  __shared__ __align__(16) __bf16 Gs[128 * 64];
  __shared__ __align__(16) __bf16 Us[128 * 64];
  const int t = threadIdx.x, w = t >> 6, l = t & 63;
  const int lm = l & 15, lq = l >> 4;
  const int wm = w >> 2, wn = w & 3;           // 2M x 4N wave grid
  const int lid = blockIdx.y * gridDim.x + blockIdx.x;
  const int xcd = lid & 7, i0 = lid >> 3;
  const int cc = i0 >> 4, jj0 = i0 & 15;
  const int m0 = (xcd * 4 + (jj0 & 3)) * 128;
  const int n0 = (cc * 4 + (jj0 >> 2)) * 128;
  const int srow = w * 8 + (l >> 3);
  const int sslot = (l & 7) ^ (l >> 3);
  const __bf16* Ap = A + (size_t)(m0 + srow) * K + sslot * 8;
  const __bf16* Gp = Gm + (size_t)(n0 + srow) * K + sslot * 8;
  const __bf16* Up = Um + (size_t)(n0 + srow) * K + sslot * 8;
  __bf16* AsW = As + w * 512;
  __bf16* GsW = Gs + w * 512;
  __bf16* UsW = Us + w * 512;
  const int sl0 = ((lq) ^ (lm & 7)) << 3;
  const int sl1 = ((4 + lq) ^ (lm & 7)) << 3;
  f32x4 accg[4][2] = {}, accu[4][2] = {};
  for (int kt = 0; kt < K; kt += 64) {
    __syncthreads();
    glds16(Ap + kt, AsW);
    glds16(Ap + (size_t)64 * K + kt, AsW + 4096);
    glds16(Gp + kt, GsW);
    glds16(Gp + (size_t)64 * K + kt, GsW + 4096);
    glds16(Up + kt, UsW);
    glds16(Up + (size_t)64 * K + kt, UsW + 4096);
    __syncthreads();
#pragma unroll
    for (int kk = 0; kk < 2; kk++) {
      const int sl = kk ? sl1 : sl0;
      bf16x8 af[4], bg[2], bu[2];
#pragma unroll
      for (int i = 0; i < 4; i++)
        af[i] = *(const bf16x8*)&As[(wm * 64 + i * 16 + lm) * 64 + sl];
#pragma unroll
      for (int j = 0; j < 2; j++) {
        bg[j] = *(const bf16x8*)&Gs[(wn * 32 + j * 16 + lm) * 64 + sl];
        bu[j] = *(const bf16x8*)&Us[(wn * 32 + j * 16 + lm) * 64 + sl];
      }
#pragma unroll
      for (int i = 0; i < 4; i++)
#pragma unroll
        for (int j = 0; j < 2; j++) {
          accg[i][j] = __builtin_amdgcn_mfma_f32_16x16x32_bf16(af[i], bg[j], accg[i][j], 0, 0, 0);
          accu[i][j] = __builtin_amdgcn_mfma_f32_16x16x32_bf16(af[i], bu[j], accu[i][j], 0, 0, 0);
        }
    }
  }
#pragma unroll
  for (int i = 0; i < 4; i++)
#pragma unroll
    for (int j = 0; j < 2; j++)
#pragma unroll
      for (int r = 0; r < 4; r++) {
        int row = m0 + wm * 64 + i * 16 + lq * 4 + r;
        int col = n0 + wn * 32 + j * 16 + lm;
        float g = accg[i][j][r];
        Cb[(size_t)row * N + col] = (__bf16)(g / (1.0f + __expf(-g)) * accu[i][j][r]);
      }
}

// ---------------- rope: out = rot_half(x) * (pm0+pm1) ----------------
__global__ __launch_bounds__(256)
void rope_kernel(const __bf16* __restrict__ qkv, const float* __restrict__ pm,
                 __bf16* __restrict__ qo, __bf16* __restrict__ ko) {
  const int row = blockIdx.x, t = threadIdx.x;
  const int s = row & 2047;
  const __bf16* q = qkv + (size_t)row * QKVN;
  const float* p0 = pm + (size_t)s * DD;
  const float* p1 = p0 + (size_t)2048 * DD;
  __bf16* qr = qo + (size_t)row * DD;
#pragma unroll
  for (int jj = 0; jj < 8; jj++) {
    int i = t + jj * 256;
    float rot = (i < 1024) ? -(float)q[i + 1024] : (float)q[i - 1024];
    qr[i] = (__bf16)(rot * (p0[i] + p1[i]));
  }
  const __bf16* k = q + 2048;
  __bf16* kr = ko + (size_t)row * KVD;
  {
    int i = t;
    float rot = (i < 128) ? -(float)k[i + 128] : (float)k[i - 128];
    kr[i] = (__bf16)(rot * (p0[i] + p1[i]));
  }
}

// ---------------- V transpose: Vt[b][d=256][k=2048] <- qkv[.,2304+d] -------
// block (kb, b): transposes a [64 k][256 d] tile through LDS. 2 MB total.
__global__ __launch_bounds__(256)
void vt_kernel(const __bf16* __restrict__ qkv, __bf16* __restrict__ vt) {
  __shared__ __bf16 sT[64][264];
  const int t = threadIdx.x;
  const int kb = blockIdx.x, b = blockIdx.y;
  const int r = t & 63;                // k row within tile
  const int c0 = t >> 6;               // 0..3
  const __bf16* src = qkv + ((size_t)(b * 2048 + kb * 64 + r)) * QKVN + 2304;
#pragma unroll
  for (int i = 0; i < 8; i++) {
    int c = c0 + i * 4;                // uint4 chunk 0..31
    *(uint4*)&sT[r][c * 8] = *(const uint4*)(src + c * 8);
  }
  __syncthreads();
  // thread t writes d-row t: 64 k values (contiguous 128B)
  __bf16* dst = vt + ((size_t)(b * 256 + t)) * 2048 + kb * 64;
  uint4 o[8];
  unsigned* ou = (unsigned*)o;
#pragma unroll
  for (int j = 0; j < 32; j++) {
    unsigned lo = *(const unsigned short*)&sT[2 * j][t];
    unsigned hi = *(const unsigned short*)&sT[2 * j + 1][t];
    ou[j] = lo | (hi << 16);
  }
#pragma unroll
  for (int i = 0; i < 8; i++) ((uint4*)dst)[i] = o[i];
}

// ---------------- attention v3: transposed-S flash, V^T input -------------
// S^T = K·Q^T -> exp in-register is the A-fragment of PV. V staged from
// pre-transposed Vt (2 uint4/lane/tile). Q fragments hoisted (loop-invariant).
// softmax = e/(sum e + 1). grid (S/128, H, B).
__global__ __launch_bounds__(256)
void attn_kernel(const __bf16* __restrict__ Q, const __bf16* __restrict__ Kb,
                 const __bf16* __restrict__ Vt, __bf16* __restrict__ O) {
  __shared__ __align__(16) __bf16 sQ[128 * 72];
  __shared__ __align__(16) __bf16 sK[64 * 72];
  __shared__ __align__(16) __bf16 sV[64 * 72];   // [d][k] (V^T)
  __shared__ float sDen[128];
  const int t = threadIdx.x, l = t & 63, w = t >> 6;
  const int lm = l & 15, lq = l >> 4;
  const int q0 = blockIdx.x * 128;
  const int h = blockIdx.y, b = blockIdx.z;
  const int p = h & 3;                 // kv slice: head h uses dims p*64..p*64+64
  const float scale = 1.0f / (16.0f + 1e-6f);
  {
    const int qr = t >> 3, qc = (t & 7) * 8;
#pragma unroll
    for (int it = 0; it < 4; it++) {
      size_t base = ((size_t)(b * 2048 + q0 + qr + it * 32)) * DD + h * 64 + qc;
      *(uint4*)&sQ[(qr + it * 32) * 72 + qc] = *(const uint4*)(Q + base);
    }
  }
  __syncthreads();
  // Q fragments (B-operand of S^T mfma) -- loop-invariant, hoisted
  bf16x8 bQ[2][2];
#pragma unroll
  for (int q_j = 0; q_j < 2; q_j++)
#pragma unroll
    for (int kk = 0; kk < 2; kk++)
      bQ[q_j][kk] = *(const bf16x8*)&sQ[(w * 32 + q_j * 16 + lm) * 72 + kk * 32 + lq * 8];
  f32x4 oacc[2][4] = {};                 // [q_j][d_n]
  float dsum[2] = {0.f, 0.f};            // per-lane partial denom, q = q_j*16+lm
  const int ksr = t >> 2, ksc = (t & 3) * 16;
  const __bf16* vrow = Vt + ((size_t)(b * 256 + p * 64 + l)) * 2048 + w * 16;
  for (int kt = 0; kt < 2048; kt += 64) {
    const __bf16* krow = Kb + ((size_t)(b * 2048 + kt + ksr)) * KVD + p * 64 + ksc;
    uint4 kv0 = *(const uint4*)(krow);
    uint4 kv1 = *(const uint4*)(krow + 8);
    uint4 vv0 = *(const uint4*)(vrow + kt);
    uint4 vv1 = *(const uint4*)(vrow + kt + 8);
    __syncthreads();
    *(uint4*)&sK[ksr * 72 + ksc] = kv0;
    *(uint4*)&sK[ksr * 72 + ksc + 8] = kv1;
    *(uint4*)&sV[l * 72 + w * 16] = vv0;
    *(uint4*)&sV[l * 72 + w * 16 + 8] = vv1;
    __syncthreads();
#pragma unroll
    for (int kt2 = 0; kt2 < 2; kt2++) {  // pairs of 16-row k_t chunks
      union { bf16x8 v; __bf16 e[8]; } pA[2];
#pragma unroll
      for (int c = 0; c < 2; c++) {
        const int kt_i = kt2 * 2 + c;
        f32x4 sacc[2] = {};
#pragma unroll
        for (int kk = 0; kk < 2; kk++) {
          bf16x8 aK = *(const bf16x8*)&sK[(kt_i * 16 + lm) * 72 + kk * 32 + lq * 8];
#pragma unroll
          for (int q_j = 0; q_j < 2; q_j++)
            sacc[q_j] = __builtin_amdgcn_mfma_f32_16x16x32_bf16(aK, bQ[q_j][kk], sacc[q_j], 0, 0, 0);
        }
#pragma unroll
        for (int q_j = 0; q_j < 2; q_j++)
#pragma unroll
          for (int r = 0; r < 4; r++) {
            float e = __expf(sacc[q_j][r] * scale);
            dsum[q_j] += e;
            pA[q_j].e[c * 4 + r] = (__bf16)e;
          }
      }
      // PV: B-frag k-permuted to match pA: j 0..3 <- k=kt2*32+lq*4+j, j 4..7 <- +16
#pragma unroll
      for (int d_n = 0; d_n < 4; d_n++) {
        union { bf16x8 v; bf16x4 h[2]; } bV;
        const __bf16* vb = &sV[(d_n * 16 + lm) * 72 + kt2 * 32 + lq * 4];
        bV.h[0] = *(const bf16x4*)(vb);
        bV.h[1] = *(const bf16x4*)(vb + 16);
#pragma unroll
        for (int q_j = 0; q_j < 2; q_j++)
          oacc[q_j][d_n] = __builtin_amdgcn_mfma_f32_16x16x32_bf16(pA[q_j].v, bV.v, oacc[q_j][d_n], 0, 0, 0);
      }
    }
  }
  // denom: reduce over lq groups (lanes lm, lm+16, lm+32, lm+48 share q)
#pragma unroll
  for (int q_j = 0; q_j < 2; q_j++) {
    dsum[q_j] += __shfl_xor(dsum[q_j], 16, 64);
    dsum[q_j] += __shfl_xor(dsum[q_j], 32, 64);
  }
  if (l < 16) {
    sDen[w * 32 + l] = dsum[0];
    sDen[w * 32 + 16 + l] = dsum[1];
  }
  __syncthreads();
#pragma unroll
  for (int q_j = 0; q_j < 2; q_j++)
#pragma unroll
    for (int d_n = 0; d_n < 4; d_n++)
#pragma unroll
      for (int r = 0; r < 4; r++) {
        int rloc = w * 32 + q_j * 16 + lq * 4 + r;
        int row = q0 + rloc;
        int col = h * 64 + d_n * 16 + lm;
        O[((size_t)(b * 2048 + row)) * DD + col] = (__bf16)(oacc[q_j][d_n][r] / (sDen[rloc] + 1.0f));
      }
}

// ---------------------------------------------------------------------------
extern "C" void kernel_launch(void* const* d_in, const int* in_sizes, int n_in,
                              void* d_out, int out_size, void* d_ws, size_t ws_size,
                              hipStream_t stream) {
  if (ws_size < WS_NEED) return;

  const float* x    = (const float*)d_in[0];
  const float* pm   = (const float*)d_in[1];
  const float* w_na = (const float*)d_in[2];
  const float* w_nf = (const float*)d_in[3];
  const float* wq   = (const float*)d_in[4];
  const float* wk   = (const float*)d_in[5];
  const float* wv   = (const float*)d_in[6];
  const float* wo   = (const float*)d_in[7];
  const float* wg   = (const float*)d_in[8];
  const float* wu   = (const float*)d_in[9];
  const float* wd   = (const float*)d_in[10];

  char* ws = (char*)d_ws;
  __bf16* wqkv_b = (__bf16*)(ws + OFF_WQKV);
  __bf16* wo_b   = (__bf16*)(ws + OFF_WO);
  __bf16* wg_b   = (__bf16*)(ws + OFF_WG);
  __bf16* wu_b   = (__bf16*)(ws + OFF_WU);
  __bf16* wdn_b  = (__bf16*)(ws + OFF_WDN);
  __bf16* h_b    = (__bf16*)(ws + OFF_H);
  __bf16* qkv_b  = (__bf16*)(ws + OFF_QKV);
  __bf16* q_b    = (__bf16*)(ws + OFF_Q);
  __bf16* k_b    = (__bf16*)(ws + OFF_K);
  __bf16* act_b  = (__bf16*)(ws + OFF_ACT);   // V^T during attn, silu*up in FFN
  float*  x1     = (float*)d_out;

  cvt_all_kernel<<<43008, 256, 0, stream>>>(wq, wk, wv, wo, wg, wu, wd,
                                            wqkv_b, wo_b, wg_b, wu_b, wdn_b);

  // ---- attention sublayer ----
  rmsnorm_kernel<<<4096, 256, 0, stream>>>(x, w_na, h_b);
  gemm_nt_kernel<0><<<dim3(20, 32), 256, 0, stream>>>(h_b, wqkv_b, qkv_b, nullptr, nullptr,
                                                      RR, QKVN, DD);
  rope_kernel<<<4096, 256, 0, stream>>>(qkv_b, pm, q_b, k_b);
  vt_kernel<<<dim3(32, 2), 256, 0, stream>>>(qkv_b, act_b);
  attn_kernel<<<dim3(16, 32, 2), 256, 0, stream>>>(q_b, k_b, act_b, h_b);
  gemm_nt_kernel<1><<<dim3(16, 32), 256, 0, stream>>>(h_b, wo_b, nullptr, x, x1,
                                                      RR, DD, DD);
  // ---- feedforward sublayer ----
  rmsnorm_kernel<<<4096, 256, 0, stream>>>(x1, w_nf, q_b);
  gemm_glu_kernel<<<dim3(44, 32), 512, 0, stream>>>(q_b, wg_b, wu_b, act_b,
                                                    RR, DFF, DD);
  gemm_nt_kernel<1><<<dim3(16, 32), 256, 0, stream>>>(act_b, wdn_b, nullptr, x1, x1,
                                                      RR, DD, DFF);
}